// Round 7
// baseline (850.984 us; speedup 1.0000x reference)
//
#include <hip/hip_runtime.h>
#include <hip/hip_bf16.h>
#include <stdint.h>

#define NGRAPH 64
#define NNODE  2048
#define NT     (NGRAPH * NNODE)   // 131072
#define KKEEP  410
#define NEG_SLOPE 0.2f

typedef __attribute__((ext_vector_type(4))) float  f32x4;
typedef __attribute__((ext_vector_type(8))) short  short8v;
typedef __attribute__((ext_vector_type(8))) __bf16 bf16x8;

// ---------------------------------------------------------------------------
// MFMA 16x16x32 bf16 — SFINAE tag-dispatch over the builtin's operand type.
// ---------------------------------------------------------------------------
template <typename A>
__device__ __forceinline__ auto mfma_call(A a, A b, f32x4 c, int)
    -> decltype(__builtin_amdgcn_mfma_f32_16x16x32_bf16(a, b, c, 0, 0, 0)) {
    return __builtin_amdgcn_mfma_f32_16x16x32_bf16(a, b, c, 0, 0, 0);
}
template <typename A>
__device__ __forceinline__ f32x4 mfma_call(A a, A b, f32x4 c, long) {
    return __builtin_amdgcn_mfma_f32_16x16x32_bf16(
        __builtin_bit_cast(bf16x8, a), __builtin_bit_cast(bf16x8, b), c, 0, 0, 0);
}
__device__ __forceinline__ f32x4 MFMA(short8v a, short8v b, f32x4 c) {
    return mfma_call(a, b, c, 0);
}

// split x = hi + lo (bf16 RNE; x-hi exact; bf16 exponent range = f32)
__device__ __forceinline__ void split_bf16(float x, short& hi, short& lo) {
    __bf16 h = (__bf16)x;
    float  hf = (float)h;
    __bf16 l = (__bf16)(x - hf);
    hi = __builtin_bit_cast(short, h);
    lo = __builtin_bit_cast(short, l);
}

__device__ __forceinline__ float leaky(float x) {
    return x >= 0.f ? x : NEG_SLOPE * x;
}
__device__ __forceinline__ float dot4(float4 a, float4 b) {
    return a.x * b.x + a.y * b.y + a.z * b.z + a.w * b.w;
}

// ---------------------------------------------------------------------------
// Fused GAT-layer GEMM, round-7 structure:
//   * B never touches LDS: pre-packed in MFMA-fragment order
//     Bp[(kblk*16+rb)*64 + lane][8] so each frag is ONE coalesced
//     global_load_dwordx4 per wave (L2-resident, consumed in-iteration ->
//     nothing async left for the barrier to drain).
//   * BK=64 (both heads of one xblk per K-step): 192 MFMA per barrier.
//   * A: reg-staged fp32 -> alpha-mix -> split -> LDS dbuf (2 x 64KB),
//     row stride 128B with XOR swizzle byte^=((row&7)<<4) on write+read.
// Accumulation order per acc element identical to rounds 5/6 (bitwise-same).
// ---------------------------------------------------------------------------
#define GBM 256
#define ASTG 65536   // one A stage: Ah 32KB | Al 32KB

template <int NVEC, int RELU>
__global__ __launch_bounds__(512, 2)
void gemm_fused(const float* __restrict__ A, const short* __restrict__ Bph,
                const short* __restrict__ Bpl, const float* __restrict__ alpha,
                const float* __restrict__ bias, const float* __restrict__ wv,
                float* __restrict__ H, float* __restrict__ dout, int Kcat) {
    extern __shared__ char smem[];
    const int tid  = threadIdx.x;
    const int lane = tid & 63;
    const int w    = tid >> 6;
    const int wm = w >> 2, wn = w & 3;
    const int R0 = (int)blockIdx.x * GBM;
    const int fr = lane & 15, kg = lane >> 4;
    const int nk = Kcat / 64;          // one iter = one xblk (both heads)
    const int Kx = Kcat >> 1;

    f32x4 acc[8][4];
#pragma unroll
    for (int m = 0; m < 8; ++m)
#pragma unroll
        for (int n = 0; n < 4; ++n) acc[m][n] = (f32x4)(0.0f);

    // A staging map: 256 rows x 32 x-cols = 2048 f32x4 chunks;
    // thread t: rows (t>>3)+64i (i=0..3), x-col chunk q = t&7.
    const int arow0 = tid >> 3;
    const int aq    = tid & 7;

    int    prow[4];
    float4 aco[4];
    float4 xv[4], xp[4];
#pragma unroll
    for (int i = 0; i < 4; ++i) {
        const int gr = R0 + arow0 + 64 * i;
        prow[i] = ((gr & (NNODE - 1)) == 0) ? gr : gr - 1;   // clamp; ain'=0 there
        aco[i]  = *reinterpret_cast<const float4*>(&alpha[(size_t)gr * 4]);
    }

    auto loadX = [&](int xblk) {
        const int col = xblk * 32 + aq * 4;
#pragma unroll
        for (int i = 0; i < 4; ++i) {
            const int gr = R0 + arow0 + 64 * i;
            xv[i] = *reinterpret_cast<const float4*>(&A[(size_t)gr * Kx + col]);
            xp[i] = *reinterpret_cast<const float4*>(&A[(size_t)prow[i] * Kx + col]);
        }
    };
    // mix (alpha, both heads) -> split -> swizzled ds_write into stage buf
    auto writeA = [&](int buf) {
        char* ahp = smem + buf * ASTG;
        char* alp = ahp + 32768;
#pragma unroll
        for (int i = 0; i < 4; ++i) {
            const int row = arow0 + 64 * i;
            const int sw  = (row & 7) << 4;
#pragma unroll
            for (int hh = 0; hh < 2; ++hh) {
                const float ain = hh ? aco[i].z : aco[i].x;
                const float asf = hh ? aco[i].w : aco[i].y;
                float y[4] = {ain * xp[i].x + asf * xv[i].x,
                              ain * xp[i].y + asf * xv[i].y,
                              ain * xp[i].z + asf * xv[i].z,
                              ain * xp[i].w + asf * xv[i].w};
                short4 hv, lv;
                split_bf16(y[0], hv.x, lv.x);
                split_bf16(y[1], hv.y, lv.y);
                split_bf16(y[2], hv.z, lv.z);
                split_bf16(y[3], hv.w, lv.w);
                const int byte = (row * 128 + hh * 64 + aq * 8) ^ sw;
                *reinterpret_cast<short4*>(ahp + byte) = hv;
                *reinterpret_cast<short4*>(alp + byte) = lv;
            }
        }
    };

    // prologue: stage tile 0
    loadX(0);
    writeA(0);
    __syncthreads();

    for (int t = 0; t < nk; ++t) {
        const int cur = t & 1, nxt = cur ^ 1;
        if (t + 1 < nk) loadX(t + 1);   // HBM latency hides under 192 MFMA

        const char* pAh = smem + cur * ASTG;
        const char* pAl = pAh + 32768;

#pragma unroll
        for (int kh = 0; kh < 2; ++kh) {
            // B frags: one coalesced dwordx4 per frag, straight to registers
            const int kblk = t * 2 + kh;
            short8v bhf[4], blf[4];
#pragma unroll
            for (int n = 0; n < 4; ++n) {
                const size_t off = ((size_t)(kblk * 16 + wn * 4 + n) * 64 + lane) * 8;
                bhf[n] = *reinterpret_cast<const short8v*>(Bph + off);
                blf[n] = *reinterpret_cast<const short8v*>(Bpl + off);
            }
            __builtin_amdgcn_s_setprio(1);
#pragma unroll
            for (int mp = 0; mp < 4; ++mp) {
                const int m0 = 2 * mp, m1 = 2 * mp + 1;
                const int rl0 = wm * 128 + m0 * 16 + fr;
                const int rl1 = wm * 128 + m1 * 16 + fr;
                const int b0 = (rl0 * 128 + kh * 64 + kg * 16) ^ ((rl0 & 7) << 4);
                const int b1 = (rl1 * 128 + kh * 64 + kg * 16) ^ ((rl1 & 7) << 4);
                const short8v ah0 = *reinterpret_cast<const short8v*>(pAh + b0);
                const short8v al0 = *reinterpret_cast<const short8v*>(pAl + b0);
                const short8v ah1 = *reinterpret_cast<const short8v*>(pAh + b1);
                const short8v al1 = *reinterpret_cast<const short8v*>(pAl + b1);
#pragma unroll
                for (int n = 0; n < 4; ++n) acc[m0][n] = MFMA(ah0, bhf[n], acc[m0][n]);
#pragma unroll
                for (int n = 0; n < 4; ++n) acc[m1][n] = MFMA(ah1, bhf[n], acc[m1][n]);
#pragma unroll
                for (int n = 0; n < 4; ++n) acc[m0][n] = MFMA(ah0, blf[n], acc[m0][n]);
#pragma unroll
                for (int n = 0; n < 4; ++n) acc[m1][n] = MFMA(ah1, blf[n], acc[m1][n]);
#pragma unroll
                for (int n = 0; n < 4; ++n) acc[m0][n] = MFMA(al0, bhf[n], acc[m0][n]);
#pragma unroll
                for (int n = 0; n < 4; ++n) acc[m1][n] = MFMA(al1, bhf[n], acc[m1][n]);
            }
            __builtin_amdgcn_s_setprio(0);
        }

        if (t + 1 < nk) writeA(nxt);
        __syncthreads();
    }

    // ---- epilogue: bias(+relu) -> H ; per-row partial dots with wv -> dout
    float bl4[4], wvl[NVEC][4];
#pragma unroll
    for (int n = 0; n < 4; ++n) {
        const int col = wn * 64 + n * 16 + fr;
        bl4[n] = bias[col];
#pragma unroll
        for (int v = 0; v < NVEC; ++v) wvl[v][n] = wv[v * 256 + col];
    }
    float* dbuf = (float*)smem;   // LDS free after final barrier

#pragma unroll
    for (int m = 0; m < 8; ++m) {
        float pd[4][NVEC];
#pragma unroll
        for (int r = 0; r < 4; ++r)
#pragma unroll
            for (int v = 0; v < NVEC; ++v) pd[r][v] = 0.f;

        const int rowb = wm * 128 + m * 16 + kg * 4;
#pragma unroll
        for (int n = 0; n < 4; ++n) {
            const int col = wn * 64 + n * 16 + fr;
            float* hp = H + (size_t)(R0 + rowb) * 256 + col;
#pragma unroll
            for (int r = 0; r < 4; ++r) {
                float hv = acc[m][n][r] + bl4[n];
                if (RELU) hv = fmaxf(hv, 0.f);
                hp[(size_t)r * 256] = hv;
#pragma unroll
                for (int v = 0; v < NVEC; ++v) pd[r][v] += hv * wvl[v][n];
            }
        }
#pragma unroll
        for (int r = 0; r < 4; ++r)
#pragma unroll
            for (int v = 0; v < NVEC; ++v) {
                float s = pd[r][v];
                s += __shfl_xor(s, 1);
                s += __shfl_xor(s, 2);
                s += __shfl_xor(s, 4);
                s += __shfl_xor(s, 8);
                if (fr == 0) dbuf[(rowb + r) * (NVEC * 4) + v * 4 + wn] = s;
            }
    }
    __syncthreads();
    if (tid < 256) {
#pragma unroll
        for (int v = 0; v < NVEC; ++v) {
            const float* d = &dbuf[tid * (NVEC * 4) + v * 4];
            dout[(size_t)(R0 + tid) * NVEC + v] = d[0] + d[1] + d[2] + d[3];
        }
    }
}

// ---------------------------------------------------------------------------
// prep: W -> fragment-packed split-bf16 B.
// idx bits: e 0-2 | lane 3-8 | rb 9-12 | kblk 13.. ; row(n) = rb*16 + (lane&15)
// kk = kblk*32 + (lane>>4)*8 + e ; kk -> (xblk, head, c); W[k][head*256+row]
// ---------------------------------------------------------------------------
__global__ __launch_bounds__(256)
void build_Bpk(const float* __restrict__ W, short* __restrict__ Bh,
               short* __restrict__ Bl, int Kx) {
    const int Kcat = 2 * Kx;
    const int idx = blockIdx.x * 256 + threadIdx.x;
    if (idx >= 256 * Kcat) return;
    const int e    = idx & 7;
    const int lane = (idx >> 3) & 63;
    const int rb   = (idx >> 9) & 15;
    const int kblk = idx >> 13;
    const int kgq = lane >> 4, frq = lane & 15;
    const int row = rb * 16 + frq;
    const int kk  = kblk * 32 + kgq * 8 + e;
    const int xblk = kk >> 6, head = (kk >> 5) & 1, c = kk & 31;
    const int k = xblk * 32 + c;
    short h, l;
    split_bf16(W[(size_t)k * 512 + head * 256 + row], h, l);
    Bh[idx] = h;
    Bl[idx] = l;
}

// wvec[vec][k] = sum_c W[k][head*256+c] * att[head][c];  vec: 0,1=src h0,h1; 2,3=dst
__global__ __launch_bounds__(256)
void build_wvec(const float* __restrict__ W, const float* __restrict__ att_src,
                const float* __restrict__ att_dst, float* __restrict__ wvec, int K) {
    const int idx = blockIdx.x * 256 + threadIdx.x;
    if (idx >= 4 * K) return;
    const int vec = idx / K, k = idx % K;
    const int head = vec & 1;
    const float* att = (vec < 2) ? att_src : att_dst;
    float s = 0.f;
    for (int c = 0; c < 256; ++c)
        s += W[(size_t)k * 512 + head * 256 + c] * att[head * 256 + c];
    wvec[idx] = s;
}

__global__ __launch_bounds__(256)
void pack_sc(const float* __restrict__ pW_root, const float* __restrict__ pW_rel,
             float* __restrict__ wsc) {
    const int t = blockIdx.x * 256 + threadIdx.x;
    if (t < 256) wsc[t] = pW_root[t];
    else if (t < 512) wsc[t] = pW_rel[t - 256];
}

// ---------------------------------------------------------------------------
// Layer-1 dots+alpha straight from x (one wave per node).
// ---------------------------------------------------------------------------
__global__ __launch_bounds__(256)
void dots_alpha_x(const float* __restrict__ x, const float* __restrict__ wvec,
                  float* __restrict__ alph) {
    const int v = blockIdx.x * 4 + (threadIdx.x >> 6);
    const int lane = threadIdx.x & 63;
    const int j = v & (NNODE - 1);

    const float4 xa = *reinterpret_cast<const float4*>(&x[(size_t)v * 512 + lane * 4]);
    const float4 xb = *reinterpret_cast<const float4*>(&x[(size_t)v * 512 + 256 + lane * 4]);
    const float4 s0a = *reinterpret_cast<const float4*>(&wvec[0 * 512 + lane * 4]);
    const float4 s0b = *reinterpret_cast<const float4*>(&wvec[0 * 512 + 256 + lane * 4]);
    const float4 s1a = *reinterpret_cast<const float4*>(&wvec[1 * 512 + lane * 4]);
    const float4 s1b = *reinterpret_cast<const float4*>(&wvec[1 * 512 + 256 + lane * 4]);
    const float4 d0a = *reinterpret_cast<const float4*>(&wvec[2 * 512 + lane * 4]);
    const float4 d0b = *reinterpret_cast<const float4*>(&wvec[2 * 512 + 256 + lane * 4]);
    const float4 d1a = *reinterpret_cast<const float4*>(&wvec[3 * 512 + lane * 4]);
    const float4 d1b = *reinterpret_cast<const float4*>(&wvec[3 * 512 + 256 + lane * 4]);

    float sv0 = dot4(xa, s0a) + dot4(xb, s0b);
    float sv1 = dot4(xa, s1a) + dot4(xb, s1b);
    float dv0 = dot4(xa, d0a) + dot4(xb, d0b);
    float dv1 = dot4(xa, d1a) + dot4(xb, d1b);
    float sp0 = 0.f, sp1 = 0.f;
    if (j > 0) {
        const float4 pa = *reinterpret_cast<const float4*>(&x[(size_t)(v - 1) * 512 + lane * 4]);
        const float4 pb = *reinterpret_cast<const float4*>(&x[(size_t)(v - 1) * 512 + 256 + lane * 4]);
        sp0 = dot4(pa, s0a) + dot4(pb, s0b);
        sp1 = dot4(pa, s1a) + dot4(pb, s1b);
    }
#pragma unroll
    for (int off = 32; off; off >>= 1) {
        sv0 += __shfl_xor(sv0, off); sv1 += __shfl_xor(sv1, off);
        dv0 += __shfl_xor(dv0, off); dv1 += __shfl_xor(dv1, off);
        sp0 += __shfl_xor(sp0, off); sp1 += __shfl_xor(sp1, off);
    }
    if (lane == 0) {
        float4 o = {0.f, 0.5f, 0.f, 0.5f};
        if (j > 0) {
            {
                const float ein = leaky(sp0 + dv0), esf = leaky(sv0 + dv0);
                const float m = fmaxf(ein, esf);
                const float win = expf(ein - m), wsf = expf(esf - m);
                const float den = win + wsf + 1e-16f;
                o.x = 0.5f * win / den; o.y = 0.5f * wsf / den;
            }
            {
                const float ein = leaky(sp1 + dv1), esf = leaky(sv1 + dv1);
                const float m = fmaxf(ein, esf);
                const float win = expf(ein - m), wsf = expf(esf - m);
                const float den = win + wsf + 1e-16f;
                o.z = 0.5f * win / den; o.w = 0.5f * wsf / den;
            }
        }
        *reinterpret_cast<float4*>(&alph[(size_t)v * 4]) = o;
    }
}

// ---------------------------------------------------------------------------
// Layer-2 alpha from epilogue raw dots {s0,s1,d0,d1}
// ---------------------------------------------------------------------------
__global__ __launch_bounds__(256)
void alpha_from_dots(const float* __restrict__ rawd, float* __restrict__ alph) {
    const int v = blockIdx.x * 256 + threadIdx.x;
    if (v >= NT) return;
    const int j = v & (NNODE - 1);
    float4 o = {0.f, 0.5f, 0.f, 0.5f};
    if (j > 0) {
        const float4 dv = *reinterpret_cast<const float4*>(&rawd[(size_t)v * 4]);
        const float4 dp = *reinterpret_cast<const float4*>(&rawd[(size_t)(v - 1) * 4]);
        {
            const float ein = leaky(dp.x + dv.z), esf = leaky(dv.x + dv.z);
            const float m = fmaxf(ein, esf);
            const float win = expf(ein - m), wsf = expf(esf - m);
            const float den = win + wsf + 1e-16f;
            o.x = 0.5f * win / den; o.y = 0.5f * wsf / den;
        }
        {
            const float ein = leaky(dp.y + dv.w), esf = leaky(dv.y + dv.w);
            const float m = fmaxf(ein, esf);
            const float win = expf(ein - m), wsf = expf(esf - m);
            const float den = win + wsf + 1e-16f;
            o.z = 0.5f * win / den; o.w = 0.5f * wsf / den;
        }
    }
    *reinterpret_cast<float4*>(&alph[(size_t)v * 4]) = o;
}

// ---------------------------------------------------------------------------
// Per-graph top-K + gated mean pool + classifier.
// score[i] = rawsc[i].x + (i>0 ? rawsc[i-1].y : 0) + pb
// ---------------------------------------------------------------------------
__global__ __launch_bounds__(1024)
void topk_pool(const float* __restrict__ rawsc, const float* __restrict__ h,
               const float* __restrict__ cls_W, const float* __restrict__ cls_b,
               const float* __restrict__ pb, float* __restrict__ out) {
    __shared__ unsigned long long keys[NNODE];
    __shared__ float sc[NNODE];
    __shared__ float partial[4][256];
    __shared__ float red[8];

    const int b = blockIdx.x;
    const int tid = threadIdx.x;
    const float pbv = pb[0];

    for (int i = tid; i < NNODE; i += 1024) {
        float v = rawsc[((size_t)b * NNODE + i) * 2] + pbv;
        if (i > 0) v += rawsc[((size_t)b * NNODE + i - 1) * 2 + 1];
        sc[i] = v;
        unsigned u = __float_as_uint(v);
        u = (u & 0x80000000u) ? ~u : (u | 0x80000000u);
        keys[i] = ((unsigned long long)(~u) << 32) | (unsigned)i;
    }
    __syncthreads();

    for (int k = 2; k <= NNODE; k <<= 1) {
        for (int jj = k >> 1; jj > 0; jj >>= 1) {
            int i = ((tid & ~(jj - 1)) << 1) | (tid & (jj - 1));
            int ixj = i | jj;
            unsigned long long a = keys[i], c = keys[ixj];
            bool up = ((i & k) == 0);
            if ((a > c) == up) { keys[i] = c; keys[ixj] = a; }
            __syncthreads();
        }
    }

    const int g = tid >> 8;
    const int c = tid & 255;
    float acc = 0.f;
    for (int kk = g; kk < KKEEP; kk += 4) {
        int idx = (int)(keys[kk] & 0xffffffffu);
        float gate = tanhf(sc[idx]);
        acc += h[((size_t)b * NNODE + idx) * 256 + c] * gate;
    }
    partial[g][c] = acc;
    __syncthreads();

    if (tid < 256) {
        float pooled = (partial[0][tid] + partial[1][tid] +
                        partial[2][tid] + partial[3][tid]) / (float)KKEEP;
        float p0 = pooled * cls_W[tid * 2 + 0];
        float p1 = pooled * cls_W[tid * 2 + 1];
#pragma unroll
        for (int off = 32; off; off >>= 1) {
            p0 += __shfl_down(p0, off);
            p1 += __shfl_down(p1, off);
        }
        if ((tid & 63) == 0) {
            red[(tid >> 6) * 2 + 0] = p0;
            red[(tid >> 6) * 2 + 1] = p1;
        }
    }
    __syncthreads();
    if (tid == 0) {
        out[b * 2 + 0] = red[0] + red[2] + red[4] + red[6] + cls_b[0];
        out[b * 2 + 1] = red[1] + red[3] + red[5] + red[7] + cls_b[1];
    }
}

// ---------------------------------------------------------------------------

extern "C" void kernel_launch(void* const* d_in, const int* in_sizes, int n_in,
                              void* d_out, int out_size, void* d_ws, size_t ws_size,
                              hipStream_t stream) {
    const float* x        = (const float*)d_in[0];
    const float* W1       = (const float*)d_in[1];
    const float* att_src1 = (const float*)d_in[2];
    const float* att_dst1 = (const float*)d_in[3];
    const float* b1       = (const float*)d_in[4];
    const float* W2       = (const float*)d_in[5];
    const float* att_src2 = (const float*)d_in[6];
    const float* att_dst2 = (const float*)d_in[7];
    const float* b2       = (const float*)d_in[8];
    const float* pW_root  = (const float*)d_in[9];
    const float* pW_rel   = (const float*)d_in[10];
    const float* pb       = (const float*)d_in[11];
    const float* cls_W    = (const float*)d_in[12];
    const float* cls_b    = (const float*)d_in[13];
    float* out = (float*)d_out;

    // workspace (~277 MB):
    float* h1     = (float*)d_ws;               // NT*256 f32
    float* h2     = h1 + (size_t)NT * 256;      // NT*256 f32
    float* alpha1 = h2 + (size_t)NT * 256;      // NT*4
    float* rawd2  = alpha1 + (size_t)NT * 4;    // NT*4
    float* alpha2 = rawd2 + (size_t)NT * 4;     // NT*4
    float* rawsc  = alpha2 + (size_t)NT * 4;    // NT*2
    short* B1h    = (short*)(rawsc + (size_t)NT * 2);  // 256*1024
    short* B1l    = B1h + 256 * 1024;
    short* B2h    = B1l + 256 * 1024;           // 256*512
    short* B2l    = B2h + 256 * 512;
    float* wvec1  = (float*)(B2l + 256 * 512);  // 4*512
    float* wvec2  = wvec1 + 4 * 512;            // 4*256
    float* wsc    = wvec2 + 4 * 256;            // 512

    // ---- prep (tiny)
    build_wvec<<<(4 * 512 + 255) / 256, 256, 0, stream>>>(W1, att_src1, att_dst1, wvec1, 512);
    build_wvec<<<(4 * 256 + 255) / 256, 256, 0, stream>>>(W2, att_src2, att_dst2, wvec2, 256);
    build_Bpk<<<(256 * 1024) / 256, 256, 0, stream>>>(W1, B1h, B1l, 512);
    build_Bpk<<<(256 * 512) / 256, 256, 0, stream>>>(W2, B2h, B2l, 256);
    pack_sc<<<2, 256, 0, stream>>>(pW_root, pW_rel, wsc);

    // ---- layer 1: alphas from x, fused mix+GEMM -> h1 (+raw dots2)
    dots_alpha_x<<<NT / 4, 256, 0, stream>>>(x, wvec1, alpha1);
    gemm_fused<4, 1><<<NT / GBM, 512, 131072, stream>>>(
        x, B1h, B1l, alpha1, b1, wvec2, h1, rawd2, 1024);

    // ---- layer 2: alpha2 from raw dots, fused mix+GEMM -> h2 (+raw score pair)
    alpha_from_dots<<<NT / 256, 256, 0, stream>>>(rawd2, alpha2);
    gemm_fused<2, 0><<<NT / GBM, 512, 131072, stream>>>(
        h1, B2h, B2l, alpha2, b2, wsc, h2, rawsc, 512);

    // ---- SAGPool top-k + gated mean pool + classifier
    topk_pool<<<NGRAPH, 1024, 0, stream>>>(rawsc, h2, cls_W, cls_b, pb, out);
}

// Round 8
// 501.581 us; speedup vs baseline: 1.6966x; 1.6966x over previous
//
#include <hip/hip_runtime.h>
#include <hip/hip_bf16.h>
#include <stdint.h>

#define NGRAPH 64
#define NNODE  2048
#define NT     (NGRAPH * NNODE)   // 131072
#define KKEEP  410
#define NEG_SLOPE 0.2f

typedef __attribute__((ext_vector_type(4))) float  f32x4;
typedef __attribute__((ext_vector_type(8))) short  short8v;
typedef __attribute__((ext_vector_type(8))) __bf16 bf16x8;

// ---------------------------------------------------------------------------
// MFMA 16x16x32 bf16 — SFINAE tag-dispatch over the builtin's operand type.
// ---------------------------------------------------------------------------
template <typename A>
__device__ __forceinline__ auto mfma_call(A a, A b, f32x4 c, int)
    -> decltype(__builtin_amdgcn_mfma_f32_16x16x32_bf16(a, b, c, 0, 0, 0)) {
    return __builtin_amdgcn_mfma_f32_16x16x32_bf16(a, b, c, 0, 0, 0);
}
template <typename A>
__device__ __forceinline__ f32x4 mfma_call(A a, A b, f32x4 c, long) {
    return __builtin_amdgcn_mfma_f32_16x16x32_bf16(
        __builtin_bit_cast(bf16x8, a), __builtin_bit_cast(bf16x8, b), c, 0, 0, 0);
}
__device__ __forceinline__ f32x4 MFMA(short8v a, short8v b, f32x4 c) {
    return mfma_call(a, b, c, 0);
}

// split x = hi + lo (bf16 RNE; x-hi exact; bf16 exponent range = f32)
__device__ __forceinline__ void split_bf16(float x, short& hi, short& lo) {
    __bf16 h = (__bf16)x;
    float  hf = (float)h;
    __bf16 l = (__bf16)(x - hf);
    hi = __builtin_bit_cast(short, h);
    lo = __builtin_bit_cast(short, l);
}

__device__ __forceinline__ void gload16(const void* g, void* lds) {
    __builtin_amdgcn_global_load_lds(
        (const __attribute__((address_space(1))) void*)g,
        (__attribute__((address_space(3))) void*)lds,
        16, 0, 0);
}

__device__ __forceinline__ float leaky(float x) {
    return x >= 0.f ? x : NEG_SLOPE * x;
}
__device__ __forceinline__ float dot4(float4 a, float4 b) {
    return a.x * b.x + a.y * b.y + a.z * b.z + a.w * b.w;
}

#define LGKM0() asm volatile("s_waitcnt lgkmcnt(0)" ::: "memory")
#define VMC8()  asm volatile("s_waitcnt vmcnt(8)"  ::: "memory")
#define VMC0()  asm volatile("s_waitcnt vmcnt(0)"  ::: "memory")

// ---------------------------------------------------------------------------
// Fused GAT-layer GEMM (R6 dataflow; round-8 change: phase-structured K-loop).
// Per K-step (BK=32), 4 phases, one per mp-pair:
//   {ds_read subtile (+p0: B frags + issueB(t+1))} ; s_barrier ; lgkmcnt(0) ;
//   setprio(1) ; 24 MFMA ; setprio(0)
// then: writeA(t+1->nxt) ; loadX(next xblk, post-writeA => ~1-iter prefetch) ;
//   lgkmcnt(0) ; vmcnt(8 if A-loads issued this iter else 0) ; gate s_barrier.
// Counted vmcnt keeps A prefetch in flight across the gate (T4); phase
// barriers + setprio give wave role-split (T3+T5). Accumulation order per acc
// element unchanged from R5/R6 -> bitwise-identical output.
// ---------------------------------------------------------------------------
#define GBM 256
#define GBK 32
#define LDS_BUF 65536
#define OFF_AL  16384
#define OFF_BH  32768
#define OFF_BL  49152

template <int NVEC, int RELU>
__global__ __launch_bounds__(512, 2)
void gemm_fused(const float* __restrict__ A, const short* __restrict__ Bth,
                const short* __restrict__ Btl, const float* __restrict__ alpha,
                const float* __restrict__ bias, const float* __restrict__ wv,
                float* __restrict__ H, float* __restrict__ dout, int Kcat) {
    extern __shared__ char smem[];
    const int tid  = threadIdx.x;
    const int lane = tid & 63;
    const int w    = tid >> 6;
    const int wm = w >> 2, wn = w & 3;
    const int R0 = (int)blockIdx.x * GBM;
    const int fr = lane & 15, kg = lane >> 4;
    const int nk = Kcat / GBK;
    const int Kx = Kcat >> 1;

    f32x4 acc[8][4];
#pragma unroll
    for (int m = 0; m < 8; ++m)
#pragma unroll
        for (int n = 0; n < 4; ++n) acc[m][n] = (f32x4)(0.0f);

    // A staging map: 256 rows x 32 x-cols = 2048 f32x4 chunks;
    // thread t: rows (t>>3)+64i (i=0..3), x-col chunk q = t&7.
    const int arow0 = tid >> 3;
    const int aq    = tid & 7;

    int    prow[4];
    float4 aco[4];
    float4 xv[4], xp[4];
#pragma unroll
    for (int i = 0; i < 4; ++i) {
        const int gr = R0 + arow0 + 64 * i;
        prow[i] = ((gr & (NNODE - 1)) == 0) ? gr : gr - 1;   // clamp; ain'=0 there
        aco[i]  = *reinterpret_cast<const float4*>(&alpha[(size_t)gr * 4]);
    }

    auto issueB = [&](int t, int buf) {
        char* bh = smem + buf * LDS_BUF + OFF_BH;
        char* bl = smem + buf * LDS_BUF + OFF_BL;
#pragma unroll
        for (int i = 0; i < 2; ++i) {
            const int rl = w * 32 + i * 16 + (lane >> 2);
            const int ks = (lane & 3) ^ ((rl >> 1) & 3);
            const size_t go = (size_t)rl * Kcat + (size_t)t * GBK + ks * 8;
            gload16(Bth + go, bh + (w * 32 + i * 16) * 64);
            gload16(Btl + go, bl + (w * 32 + i * 16) * 64);
        }
    };
    auto loadX = [&](int xblk) {
        const int col = xblk * 32 + aq * 4;
#pragma unroll
        for (int i = 0; i < 4; ++i) {
            const int gr = R0 + arow0 + 64 * i;
            xv[i] = *reinterpret_cast<const float4*>(&A[(size_t)gr * Kx + col]);
            xp[i] = *reinterpret_cast<const float4*>(&A[(size_t)prow[i] * Kx + col]);
        }
    };
    auto writeA = [&](int tt, int buf) {
        char* ahp = smem + buf * LDS_BUF;
        char* alp = ahp + OFF_AL;
        const int hh = tt & 1;
#pragma unroll
        for (int i = 0; i < 4; ++i) {
            const float ain = hh ? aco[i].z : aco[i].x;
            const float asf = hh ? aco[i].w : aco[i].y;
            float y[4] = {ain * xp[i].x + asf * xv[i].x,
                          ain * xp[i].y + asf * xv[i].y,
                          ain * xp[i].z + asf * xv[i].z,
                          ain * xp[i].w + asf * xv[i].w};
            short4 hv, lv;
            split_bf16(y[0], hv.x, lv.x);
            split_bf16(y[1], hv.y, lv.y);
            split_bf16(y[2], hv.z, lv.z);
            split_bf16(y[3], hv.w, lv.w);
            const int row  = arow0 + 64 * i;
            const int byte = (row * 64 + (((aq >> 1) ^ ((row >> 1) & 3)) << 4) + (aq & 1) * 8);
            *reinterpret_cast<short4*>(ahp + byte) = hv;
            *reinterpret_cast<short4*>(alp + byte) = lv;
        }
    };

    // prologue: stage tile 0 (xblk0/head0) into buf0
    issueB(0, 0);
    loadX(0);
    writeA(0, 0);     // compiler A-wait drains B(0) too (older, in-order)
    LGKM0();
    VMC0();
    __builtin_amdgcn_s_barrier();

    for (int t = 0; t < nk; ++t) {
        const int cur = t & 1, nxt = cur ^ 1;
        const char* pAh = smem + cur * LDS_BUF;
        const char* pAl = pAh + OFF_AL;
        const char* pBh = pAh + OFF_BH;
        const char* pBl = pAh + OFF_BL;

        short8v bhf[4], blf[4];
#pragma unroll
        for (int mp = 0; mp < 4; ++mp) {
            if (mp == 0) {
                // phase 0 extras: B frags for the whole K-step + next-B issue
#pragma unroll
                for (int n = 0; n < 4; ++n) {
                    const int rl   = wn * 64 + n * 16 + fr;
                    const int byte = rl * 64 + ((kg ^ ((rl >> 1) & 3)) << 4);
                    bhf[n] = *reinterpret_cast<const short8v*>(pBh + byte);
                    blf[n] = *reinterpret_cast<const short8v*>(pBl + byte);
                }
                if (t + 1 < nk) issueB(t + 1, nxt);
            }
            const int m0 = 2 * mp, m1 = m0 + 1;
            const int rl0 = wm * 128 + m0 * 16 + fr;
            const int rl1 = wm * 128 + m1 * 16 + fr;
            const int b0 = rl0 * 64 + ((kg ^ ((rl0 >> 1) & 3)) << 4);
            const int b1 = rl1 * 64 + ((kg ^ ((rl1 >> 1) & 3)) << 4);
            const short8v ah0 = *reinterpret_cast<const short8v*>(pAh + b0);
            const short8v al0 = *reinterpret_cast<const short8v*>(pAl + b0);
            const short8v ah1 = *reinterpret_cast<const short8v*>(pAh + b1);
            const short8v al1 = *reinterpret_cast<const short8v*>(pAl + b1);

            __builtin_amdgcn_s_barrier();   // phase convergence (scheduling only)
            LGKM0();
            __builtin_amdgcn_s_setprio(1);
#pragma unroll
            for (int n = 0; n < 4; ++n) acc[m0][n] = MFMA(ah0, bhf[n], acc[m0][n]);
#pragma unroll
            for (int n = 0; n < 4; ++n) acc[m1][n] = MFMA(ah1, bhf[n], acc[m1][n]);
#pragma unroll
            for (int n = 0; n < 4; ++n) acc[m0][n] = MFMA(ah0, blf[n], acc[m0][n]);
#pragma unroll
            for (int n = 0; n < 4; ++n) acc[m1][n] = MFMA(ah1, blf[n], acc[m1][n]);
#pragma unroll
            for (int n = 0; n < 4; ++n) acc[m0][n] = MFMA(al0, bhf[n], acc[m0][n]);
#pragma unroll
            for (int n = 0; n < 4; ++n) acc[m1][n] = MFMA(al1, bhf[n], acc[m1][n]);
            __builtin_amdgcn_s_setprio(0);
        }

        // tail: stage next A tile into nxt, prefetch next xblk, gated barrier
        const bool dl = ((t & 1) == 0) && (t / 2 + 1 < nk / 2);
        if (t + 1 < nk) {
            writeA(t + 1, nxt);     // consumes xv/xp (loaded >=1 iter ago)
            if (dl) loadX(t / 2 + 1);   // issue AFTER last use of current xblk
        }
        LGKM0();                    // ds_writes visible before gate
        if (t + 1 < nk) {
            if (dl) VMC8();         // retire 4 older B-gloads, keep 8 A in flight
            else    VMC0();         // only B outstanding -> drain (cheap, L2)
        }
        __builtin_amdgcn_s_barrier();   // gate: nxt buffer valid for t+1
    }

    // ---- epilogue: bias(+relu) -> H ; per-row partial dots with wv -> dout
    float bl4[4], wvl[NVEC][4];
#pragma unroll
    for (int n = 0; n < 4; ++n) {
        const int col = wn * 64 + n * 16 + fr;
        bl4[n] = bias[col];
#pragma unroll
        for (int v = 0; v < NVEC; ++v) wvl[v][n] = wv[v * 256 + col];
    }
    float* dbuf = (float*)smem;   // buf0 region; untouched during last iter

#pragma unroll
    for (int m = 0; m < 8; ++m) {
        float pd[4][NVEC];
#pragma unroll
        for (int r = 0; r < 4; ++r)
#pragma unroll
            for (int v = 0; v < NVEC; ++v) pd[r][v] = 0.f;

        const int rowb = wm * 128 + m * 16 + kg * 4;
#pragma unroll
        for (int n = 0; n < 4; ++n) {
            const int col = wn * 64 + n * 16 + fr;
            float* hp = H + (size_t)(R0 + rowb) * 256 + col;
#pragma unroll
            for (int r = 0; r < 4; ++r) {
                float hv = acc[m][n][r] + bl4[n];
                if (RELU) hv = fmaxf(hv, 0.f);
                hp[(size_t)r * 256] = hv;
#pragma unroll
                for (int v = 0; v < NVEC; ++v) pd[r][v] += hv * wvl[v][n];
            }
        }
#pragma unroll
        for (int r = 0; r < 4; ++r)
#pragma unroll
            for (int v = 0; v < NVEC; ++v) {
                float s = pd[r][v];
                s += __shfl_xor(s, 1);
                s += __shfl_xor(s, 2);
                s += __shfl_xor(s, 4);
                s += __shfl_xor(s, 8);
                if (fr == 0) dbuf[(rowb + r) * (NVEC * 4) + v * 4 + wn] = s;
            }
    }
    __syncthreads();
    if (tid < 256) {
#pragma unroll
        for (int v = 0; v < NVEC; ++v) {
            const float* d = &dbuf[tid * (NVEC * 4) + v * 4];
            dout[(size_t)(R0 + tid) * NVEC + v] = d[0] + d[1] + d[2] + d[3];
        }
    }
}

// ---------------------------------------------------------------------------
// prep: Bcat[n][kk] split/transposed, kk = xblk*64 + head*32 + c
// ---------------------------------------------------------------------------
__global__ __launch_bounds__(256)
void build_B(const float* __restrict__ W, short* __restrict__ Bth,
             short* __restrict__ Btl, int Kx) {
    const int Kcat = 2 * Kx;
    const int idx = blockIdx.x * 256 + threadIdx.x;
    if (idx >= 256 * Kcat) return;
    const int n = idx / Kcat, kk = idx % Kcat;
    const int xblk = kk >> 6, rem = kk & 63, head = rem >> 5, c = rem & 31;
    const int k = xblk * 32 + c;
    short h, l;
    split_bf16(W[(size_t)k * 512 + head * 256 + n], h, l);
    Bth[idx] = h;
    Btl[idx] = l;
}

// wvec[vec][k] = sum_c W[k][head*256+c] * att[head][c];  vec: 0,1=src h0,h1; 2,3=dst
__global__ __launch_bounds__(256)
void build_wvec(const float* __restrict__ W, const float* __restrict__ att_src,
                const float* __restrict__ att_dst, float* __restrict__ wvec, int K) {
    const int idx = blockIdx.x * 256 + threadIdx.x;
    if (idx >= 4 * K) return;
    const int vec = idx / K, k = idx % K;
    const int head = vec & 1;
    const float* att = (vec < 2) ? att_src : att_dst;
    float s = 0.f;
    for (int c = 0; c < 256; ++c)
        s += W[(size_t)k * 512 + head * 256 + c] * att[head * 256 + c];
    wvec[idx] = s;
}

__global__ __launch_bounds__(256)
void pack_sc(const float* __restrict__ pW_root, const float* __restrict__ pW_rel,
             float* __restrict__ wsc) {
    const int t = blockIdx.x * 256 + threadIdx.x;
    if (t < 256) wsc[t] = pW_root[t];
    else if (t < 512) wsc[t] = pW_rel[t - 256];
}

// ---------------------------------------------------------------------------
// Layer-1 raw dots from x only (one wave per node): {s0,s1,d0,d1}.
// (v-1's src-dot is v-1's own s — no second row read; alpha_from_dots pairs.)
// ---------------------------------------------------------------------------
__global__ __launch_bounds__(256)
void dots_x(const float* __restrict__ x, const float* __restrict__ wvec,
            float* __restrict__ rawd) {
    const int v = blockIdx.x * 4 + (threadIdx.x >> 6);
    const int lane = threadIdx.x & 63;

    const float4 xa = *reinterpret_cast<const float4*>(&x[(size_t)v * 512 + lane * 4]);
    const float4 xb = *reinterpret_cast<const float4*>(&x[(size_t)v * 512 + 256 + lane * 4]);
    const float4 s0a = *reinterpret_cast<const float4*>(&wvec[0 * 512 + lane * 4]);
    const float4 s0b = *reinterpret_cast<const float4*>(&wvec[0 * 512 + 256 + lane * 4]);
    const float4 s1a = *reinterpret_cast<const float4*>(&wvec[1 * 512 + lane * 4]);
    const float4 s1b = *reinterpret_cast<const float4*>(&wvec[1 * 512 + 256 + lane * 4]);
    const float4 d0a = *reinterpret_cast<const float4*>(&wvec[2 * 512 + lane * 4]);
    const float4 d0b = *reinterpret_cast<const float4*>(&wvec[2 * 512 + 256 + lane * 4]);
    const float4 d1a = *reinterpret_cast<const float4*>(&wvec[3 * 512 + lane * 4]);
    const float4 d1b = *reinterpret_cast<const float4*>(&wvec[3 * 512 + 256 + lane * 4]);

    float sv0 = dot4(xa, s0a) + dot4(xb, s0b);
    float sv1 = dot4(xa, s1a) + dot4(xb, s1b);
    float dv0 = dot4(xa, d0a) + dot4(xb, d0b);
    float dv1 = dot4(xa, d1a) + dot4(xb, d1b);
#pragma unroll
    for (int off = 32; off; off >>= 1) {
        sv0 += __shfl_xor(sv0, off); sv1 += __shfl_xor(sv1, off);
        dv0 += __shfl_xor(dv0, off); dv1 += __shfl_xor(dv1, off);
    }
    if (lane == 0) {
        float4 o = {sv0, sv1, dv0, dv1};
        *reinterpret_cast<float4*>(&rawd[(size_t)v * 4]) = o;
    }
}

// ---------------------------------------------------------------------------
// alpha from raw dots {s0,s1,d0,d1} (both layers)
// ---------------------------------------------------------------------------
__global__ __launch_bounds__(256)
void alpha_from_dots(const float* __restrict__ rawd, float* __restrict__ alph) {
    const int v = blockIdx.x * 256 + threadIdx.x;
    if (v >= NT) return;
    const int j = v & (NNODE - 1);
    float4 o = {0.f, 0.5f, 0.f, 0.5f};
    if (j > 0) {
        const float4 dv = *reinterpret_cast<const float4*>(&rawd[(size_t)v * 4]);
        const float4 dp = *reinterpret_cast<const float4*>(&rawd[(size_t)(v - 1) * 4]);
        {
            const float ein = leaky(dp.x + dv.z), esf = leaky(dv.x + dv.z);
            const float m = fmaxf(ein, esf);
            const float win = expf(ein - m), wsf = expf(esf - m);
            const float den = win + wsf + 1e-16f;
            o.x = 0.5f * win / den; o.y = 0.5f * wsf / den;
        }
        {
            const float ein = leaky(dp.y + dv.w), esf = leaky(dv.y + dv.w);
            const float m = fmaxf(ein, esf);
            const float win = expf(ein - m), wsf = expf(esf - m);
            const float den = win + wsf + 1e-16f;
            o.z = 0.5f * win / den; o.w = 0.5f * wsf / den;
        }
    }
    *reinterpret_cast<float4*>(&alph[(size_t)v * 4]) = o;
}

// ---------------------------------------------------------------------------
// Per-graph top-K + gated mean pool + classifier.
// score[i] = rawsc[i].x + (i>0 ? rawsc[i-1].y : 0) + pb
// ---------------------------------------------------------------------------
__global__ __launch_bounds__(1024)
void topk_pool(const float* __restrict__ rawsc, const float* __restrict__ h,
               const float* __restrict__ cls_W, const float* __restrict__ cls_b,
               const float* __restrict__ pb, float* __restrict__ out) {
    __shared__ unsigned long long keys[NNODE];
    __shared__ float sc[NNODE];
    __shared__ float partial[4][256];
    __shared__ float red[8];

    const int b = blockIdx.x;
    const int tid = threadIdx.x;
    const float pbv = pb[0];

    for (int i = tid; i < NNODE; i += 1024) {
        float v = rawsc[((size_t)b * NNODE + i) * 2] + pbv;
        if (i > 0) v += rawsc[((size_t)b * NNODE + i - 1) * 2 + 1];
        sc[i] = v;
        unsigned u = __float_as_uint(v);
        u = (u & 0x80000000u) ? ~u : (u | 0x80000000u);
        keys[i] = ((unsigned long long)(~u) << 32) | (unsigned)i;
    }
    __syncthreads();

    for (int k = 2; k <= NNODE; k <<= 1) {
        for (int jj = k >> 1; jj > 0; jj >>= 1) {
            int i = ((tid & ~(jj - 1)) << 1) | (tid & (jj - 1));
            int ixj = i | jj;
            unsigned long long a = keys[i], c = keys[ixj];
            bool up = ((i & k) == 0);
            if ((a > c) == up) { keys[i] = c; keys[ixj] = a; }
            __syncthreads();
        }
    }

    const int g = tid >> 8;
    const int c = tid & 255;
    float acc = 0.f;
    for (int kk = g; kk < KKEEP; kk += 4) {
        int idx = (int)(keys[kk] & 0xffffffffu);
        float gate = tanhf(sc[idx]);
        acc += h[((size_t)b * NNODE + idx) * 256 + c] * gate;
    }
    partial[g][c] = acc;
    __syncthreads();

    if (tid < 256) {
        float pooled = (partial[0][tid] + partial[1][tid] +
                        partial[2][tid] + partial[3][tid]) / (float)KKEEP;
        float p0 = pooled * cls_W[tid * 2 + 0];
        float p1 = pooled * cls_W[tid * 2 + 1];
#pragma unroll
        for (int off = 32; off; off >>= 1) {
            p0 += __shfl_down(p0, off);
            p1 += __shfl_down(p1, off);
        }
        if ((tid & 63) == 0) {
            red[(tid >> 6) * 2 + 0] = p0;
            red[(tid >> 6) * 2 + 1] = p1;
        }
    }
    __syncthreads();
    if (tid == 0) {
        out[b * 2 + 0] = red[0] + red[2] + red[4] + red[6] + cls_b[0];
        out[b * 2 + 1] = red[1] + red[3] + red[5] + red[7] + cls_b[1];
    }
}

// ---------------------------------------------------------------------------

extern "C" void kernel_launch(void* const* d_in, const int* in_sizes, int n_in,
                              void* d_out, int out_size, void* d_ws, size_t ws_size,
                              hipStream_t stream) {
    const float* x        = (const float*)d_in[0];
    const float* W1       = (const float*)d_in[1];
    const float* att_src1 = (const float*)d_in[2];
    const float* att_dst1 = (const float*)d_in[3];
    const float* b1       = (const float*)d_in[4];
    const float* W2       = (const float*)d_in[5];
    const float* att_src2 = (const float*)d_in[6];
    const float* att_dst2 = (const float*)d_in[7];
    const float* b2       = (const float*)d_in[8];
    const float* pW_root  = (const float*)d_in[9];
    const float* pW_rel   = (const float*)d_in[10];
    const float* pb       = (const float*)d_in[11];
    const float* cls_W    = (const float*)d_in[12];
    const float* cls_b    = (const float*)d_in[13];
    float* out = (float*)d_out;

    // workspace (~279 MB):
    float* h1     = (float*)d_ws;               // NT*256 f32
    float* h2     = h1 + (size_t)NT * 256;      // NT*256 f32
    float* alpha1 = h2 + (size_t)NT * 256;      // NT*4
    float* rawd1  = alpha1 + (size_t)NT * 4;    // NT*4
    float* rawd2  = rawd1 + (size_t)NT * 4;     // NT*4
    float* alpha2 = rawd2 + (size_t)NT * 4;     // NT*4
    float* rawsc  = alpha2 + (size_t)NT * 4;    // NT*2
    short* B1h    = (short*)(rawsc + (size_t)NT * 2);  // 256*1024
    short* B1l    = B1h + 256 * 1024;
    short* B2h    = B1l + 256 * 1024;           // 256*512
    short* B2l    = B2h + 256 * 512;
    float* wvec1  = (float*)(B2l + 256 * 512);  // 4*512
    float* wvec2  = wvec1 + 4 * 512;            // 4*256
    float* wsc    = wvec2 + 4 * 256;            // 512

    // ---- prep (tiny)
    build_wvec<<<(4 * 512 + 255) / 256, 256, 0, stream>>>(W1, att_src1, att_dst1, wvec1, 512);
    build_wvec<<<(4 * 256 + 255) / 256, 256, 0, stream>>>(W2, att_src2, att_dst2, wvec2, 256);
    build_B<<<(256 * 1024) / 256, 256, 0, stream>>>(W1, B1h, B1l, 512);
    build_B<<<(256 * 512) / 256, 256, 0, stream>>>(W2, B2h, B2l, 256);
    pack_sc<<<2, 256, 0, stream>>>(pW_root, pW_rel, wsc);

    // ---- layer 1: raw dots from x (single x-pass), alpha, fused mix+GEMM -> h1
    dots_x<<<NT / 4, 256, 0, stream>>>(x, wvec1, rawd1);
    alpha_from_dots<<<NT / 256, 256, 0, stream>>>(rawd1, alpha1);
    gemm_fused<4, 1><<<NT / GBM, 512, 131072, stream>>>(
        x, B1h, B1l, alpha1, b1, wvec2, h1, rawd2, 1024);

    // ---- layer 2: alpha2 from epilogue dots, fused mix+GEMM -> h2 (+score pair)
    alpha_from_dots<<<NT / 256, 256, 0, stream>>>(rawd2, alpha2);
    gemm_fused<2, 0><<<NT / GBM, 512, 131072, stream>>>(
        h1, B2h, B2l, alpha2, b2, wsc, h2, rawsc, 512);

    // ---- SAGPool top-k + gated mean pool + classifier
    topk_pool<<<NGRAPH, 1024, 0, stream>>>(rawsc, h2, cls_W, cls_b, pb, out);
}